// Round 7
// baseline (212.335 us; speedup 1.0000x reference)
//
#include <hip/hip_runtime.h>

// BandSplit R7: compose the whole linear op into a banded matrix M (+bias),
// then one dense banded GEMM. M[(c,f),(c',f')] = sum_k post'_k·pre'_k with
// melw/mask/(1/ola) folded; band contiguity => |f-f'| <= W-1 <= 111.
// Pipeline: memset(Mf32+bias) -> pack_preT/pack_post (bf16 frags) ->
// compose<even>(store)/compose<odd>(+=) -> convert Mf32->bf16 B-frags ->
// main banded GEMM (9 f-chunks x 128 t-tiles), plain coalesced stores.

#define K_BANDS 64
#define COUT_D  128
#define T_DIM   1024
#define B_DIM   4
#define F_DIM   1025
#define WPAD    112      // padded band width (W <= 112, verified R2-R6)
#define DINP    224      // 2*WPAD, channel-blocked j/i = c*112 + wi
#define NMT     14       // DINP/16 tiles
#define NKTC    4        // 128/32 compose-K tiles
#define CHUNK   128      // output f-bins per chunk
#define NCHUNK  9        // ceil(1025/128)
#define WIN     352      // 112 + 128 + 112 input window
#define K2      704      // 2*WIN
#define KT2     22       // K2/32
#define OC      256      // out cols per chunk (2ch x 128)
#define NCT     16       // OC/16
#define M_TILE  32       // rows per main block
#define SXLD    712      // s_x row stride (shorts): 356 dw %32=4 -> 2-way free

typedef __attribute__((ext_vector_type(8))) short bf16x8;
typedef __attribute__((ext_vector_type(4))) float f32x4;

__device__ __forceinline__ unsigned short f2bf(float f) {
    unsigned u = __builtin_bit_cast(unsigned, f);
    u += 0x7FFFu + ((u >> 16) & 1u);          // RNE
    return (unsigned short)(u >> 16);
}
__device__ __forceinline__ void st8(unsigned short* o, const unsigned short* v) {
    *(ushort4*)(o)     = make_ushort4(v[0], v[1], v[2], v[3]);
    *(ushort4*)(o + 4) = make_ushort4(v[4], v[5], v[6], v[7]);
}

struct alignas(4) f4u { float v[4]; };        // dword-aligned 16B load

// ---- pack pre'^T as MFMA A-frags: (k, kt over o, mt over j, lane, 8)
// value = wt(j) * pre_w[j_ref, o];  j = mt*16+(lane&15), o = kt*32+kg*8+e
__global__ __launch_bounds__(256) void bs_pack_preT(
    const float* __restrict__ pre_w, const float* __restrict__ melw,
    const float* __restrict__ mask, unsigned short* __restrict__ dst,
    int W, int din)
{
    const int k = blockIdx.x, kt = blockIdx.y;
    for (int q = threadIdx.x; q < NMT * 64; q += 256) {
        const int mt = q >> 6, lane = q & 63;
        const int j  = mt * 16 + (lane & 15);
        const int kg = lane >> 4;
        const int cc = (j >= WPAD);
        const int wi = j - cc * WPAD;
        float wt = 0.f;
        if (wi < W) wt = melw[k * W + wi] * mask[k * W + wi];
        unsigned short v[8];
#pragma unroll
        for (int e = 0; e < 8; ++e) {
            const int o = kt * 32 + kg * 8 + e;
            const float f = (wt != 0.f)
                ? wt * pre_w[((size_t)k * din + (2 * wi + cc)) * COUT_D + o] : 0.f;
            v[e] = f2bf(f);
        }
        st8(dst + ((((size_t)k * NKTC + kt) * NMT + mt) * 64 + lane) * 8, v);
    }
}

// ---- pack post' as MFMA B-frags: (k, kt over o, ct over i, lane, 8), * sc(i)
__global__ __launch_bounds__(256) void bs_pack_post(
    const float* __restrict__ post_w, const int* __restrict__ idx,
    const float* __restrict__ melw, const float* __restrict__ mask,
    const float* __restrict__ ola, unsigned short* __restrict__ dst,
    int W, int din)
{
    const int k = blockIdx.x, kt = blockIdx.y;
    for (int q = threadIdx.x; q < NMT * 64; q += 256) {
        const int ct = q >> 6, lane = q & 63;
        const int col = lane & 15, kg = lane >> 4;
        const int i  = ct * 16 + col;
        const int cc = (i >= WPAD);
        const int wi = i - cc * WPAD;
        float sc = 0.f;
        if (wi < W) {
            const float mw = melw[k * W + wi] * mask[k * W + wi];
            if (mw != 0.f) sc = 1.0f / ola[idx[k * W + wi]];
        }
        unsigned short v[8];
#pragma unroll
        for (int e = 0; e < 8; ++e) {
            const int o = kt * 32 + kg * 8 + e;
            const float f = (sc != 0.f)
                ? sc * post_w[((size_t)k * COUT_D + o) * din + 2 * wi + cc] : 0.f;
            v[e] = f2bf(f);
        }
        st8(dst + ((((size_t)k * NKTC + kt) * NMT + ct) * 64 + lane) * 8, v);
    }
}

// ---- compose A_k = pre'^T x post' (224x224, K=128) and scatter into banded
// Mf32 + bias.  Even bands: plain store (supports disjoint, Mf pre-zeroed);
// odd bands: read-add-store, stream-ordered after even.
template <int PARITY>
__global__ __launch_bounds__(256) void bs_compose(
    const unsigned short* __restrict__ preT,
    const unsigned short* __restrict__ postP,
    const float* __restrict__ pre_b,  const float* __restrict__ post_w,
    const float* __restrict__ post_b, const int* __restrict__ idx,
    const float* __restrict__ melw,   const float* __restrict__ mask,
    const float* __restrict__ ola,
    float* __restrict__ Mf, float* __restrict__ bias_g, int W, int din)
{
    __shared__ unsigned char s_flag[DINP];
    const int k   = blockIdx.x * 2 + PARITY;
    const int tid = threadIdx.x;
    const int f0  = idx[(size_t)k * W];

    bool myflag = false;
    if (tid < DINP) {
        const int cc = tid >= WPAD, wi = tid - cc * WPAD;
        myflag = (wi < W) && (melw[k * W + wi] * mask[k * W + wi] != 0.f);
        s_flag[tid] = myflag;
    }
    __syncthreads();

    const int lane = tid & 63, wave = tid >> 6;
    const int col  = lane & 15, kg  = lane >> 4;
    const bf16x8* ap = (const bf16x8*)(preT  + (size_t)k * NKTC * NMT * 512);
    const bf16x8* bp = (const bf16x8*)(postP + (size_t)k * NKTC * NMT * 512);

    for (int mt = wave; mt < NMT; mt += 4) {
        bf16x8 a[NKTC];
#pragma unroll
        for (int kt = 0; kt < NKTC; ++kt) a[kt] = ap[(kt * NMT + mt) * 64 + lane];
        for (int nt = 0; nt < NMT; ++nt) {
            f32x4 acc = (f32x4){0.f, 0.f, 0.f, 0.f};
#pragma unroll
            for (int kt = 0; kt < NKTC; ++kt)
                acc = __builtin_amdgcn_mfma_f32_16x16x32_bf16(
                    a[kt], bp[(kt * NMT + nt) * 64 + lane], acc, 0, 0, 0);
            const int i_loc = nt * 16 + col;
            if (!s_flag[i_loc]) continue;
            const int c  = i_loc >= WPAD, wi = i_loc - c * WPAD;
            const int f  = f0 + wi;
            const int ch = f >> 7, df = f & 127;
            const int lo = (ch << 7) - WPAD;
            const size_t colIdx = (size_t)(c * CHUNK + df);
#pragma unroll
            for (int reg = 0; reg < 4; ++reg) {
                const int j_loc = mt * 16 + kg * 4 + reg;
                if (!s_flag[j_loc]) continue;
                const int c2 = j_loc >= WPAD, wi2 = j_loc - c2 * WPAD;
                const int jj = f0 + wi2 - lo;          // in [1, 350]
                float* p = Mf + ((size_t)ch * K2 + c2 * WIN + jj) * OC + colIdx;
                if (PARITY == 0) *p = acc[reg];
                else             *p = *p + acc[reg];
            }
        }
    }

    // bias[(c,f)] = sc * (pre_b . post_w[:, i] + post_b[i])
    if (tid < DINP && myflag) {
        const int c = tid >= WPAD, wi = tid - c * WPAD;
        const int f = f0 + wi;
        const float sc = 1.0f / ola[f];
        float v = post_b[(size_t)k * din + 2 * wi + c];
        for (int o = 0; o < COUT_D; ++o)
            v += pre_b[k * COUT_D + o]
                 * post_w[((size_t)k * COUT_D + o) * din + 2 * wi + c];
        v *= sc;
        float* p = bias_g + c * F_DIM + f;
        if (PARITY == 0) *p = v;
        else             *p = *p + v;
    }
}

// ---- convert banded Mf32 -> bf16 B-frags: (chunk, kt, ct, lane, 8)
__global__ __launch_bounds__(256) void bs_mk_bf16(
    const float* __restrict__ Mf, unsigned short* __restrict__ Mb)
{
    const int chunk = blockIdx.x, kt = blockIdx.y;
    for (int q = threadIdx.x; q < NCT * 64; q += 256) {
        const int ct = q >> 6, lane = q & 63;
        const int col = lane & 15, kg = lane >> 4;
        unsigned short v[8];
#pragma unroll
        for (int e = 0; e < 8; ++e) {
            const int jp = kt * 32 + kg * 8 + e;
            v[e] = f2bf(Mf[((size_t)chunk * K2 + jp) * OC + ct * 16 + col]);
        }
        st8(Mb + ((((size_t)chunk * KT2 + kt) * NCT + ct) * 64 + lane) * 8, v);
    }
}

// ---- main: out_row = M . x_window + bias.  Plain dense stores, no memset.
__global__ __launch_bounds__(256) void bs_banded(
    const float* __restrict__ x, const unsigned short* __restrict__ Mb,
    const float* __restrict__ bias_g, float* __restrict__ out)
{
    __shared__ unsigned short s_x[M_TILE][SXLD];

    const int chunk  = blockIdx.x;
    const int m_base = blockIdx.y * M_TILE;
    const int tid    = threadIdx.x;
    const int lo     = chunk * CHUNK - WPAD;      // may be negative / past end

    // stage raw x window -> bf16 LDS (weights live in M; OOB -> clamped addr,
    // values killed by zero M rows)
    for (int p = tid; p < M_TILE * 2 * 88; p += 256) {
        const int seg = p / 88, q = p - seg * 88;
        const int row = seg >> 1, c = seg & 1;
        const int m = m_base + row, b = m >> 10, t = m & 1023;
        const float* xr = x + ((size_t)(b * 2 + c) * T_DIM + t) * F_DIM;
        const int fl = lo + 4 * q;
        float v0, v1, v2, v3;
        if (fl >= 0 && fl + 4 <= F_DIM) {
            const f4u vv = *reinterpret_cast<const f4u*>(xr + fl);
            v0 = vv.v[0]; v1 = vv.v[1]; v2 = vv.v[2]; v3 = vv.v[3];
        } else {
            const int e0 = min(max(fl, 0),     F_DIM - 1);
            const int e1 = min(max(fl + 1, 0), F_DIM - 1);
            const int e2 = min(max(fl + 2, 0), F_DIM - 1);
            const int e3 = min(max(fl + 3, 0), F_DIM - 1);
            v0 = xr[e0]; v1 = xr[e1]; v2 = xr[e2]; v3 = xr[e3];
        }
        const unsigned w0 = (unsigned)f2bf(v0) | ((unsigned)f2bf(v1) << 16);
        const unsigned w1 = (unsigned)f2bf(v2) | ((unsigned)f2bf(v3) << 16);
        unsigned* d = (unsigned*)&s_x[row][c * WIN + 4 * q];
        d[0] = w0; d[1] = w1;
    }
    __syncthreads();

    const int lane = tid & 63, wave = tid >> 6;
    const int col  = lane & 15, kg  = lane >> 4;

    f32x4 acc[4][2];
#pragma unroll
    for (int ctl = 0; ctl < 4; ++ctl)
#pragma unroll
        for (int mf = 0; mf < 2; ++mf) acc[ctl][mf] = (f32x4){0.f, 0.f, 0.f, 0.f};

    const bf16x8* bp = (const bf16x8*)(Mb + (size_t)chunk * KT2 * NCT * 512);
    bf16x8 bnx[4];
#pragma unroll
    for (int ctl = 0; ctl < 4; ++ctl)
        bnx[ctl] = bp[(size_t)(0 * NCT + wave * 4 + ctl) * 64 + lane];

    for (int kt = 0; kt < KT2; ++kt) {
        bf16x8 bc[4];
#pragma unroll
        for (int ctl = 0; ctl < 4; ++ctl) bc[ctl] = bnx[ctl];
        if (kt + 1 < KT2) {
#pragma unroll
            for (int ctl = 0; ctl < 4; ++ctl)
                bnx[ctl] = bp[(size_t)((kt + 1) * NCT + wave * 4 + ctl) * 64 + lane];
        }
        const bf16x8 a0 = *(const bf16x8*)&s_x[col][kt * 32 + kg * 8];
        const bf16x8 a1 = *(const bf16x8*)&s_x[16 + col][kt * 32 + kg * 8];
#pragma unroll
        for (int ctl = 0; ctl < 4; ++ctl) {
            acc[ctl][0] = __builtin_amdgcn_mfma_f32_16x16x32_bf16(
                a0, bc[ctl], acc[ctl][0], 0, 0, 0);
            acc[ctl][1] = __builtin_amdgcn_mfma_f32_16x16x32_bf16(
                a1, bc[ctl], acc[ctl][1], 0, 0, 0);
        }
    }

    // epilogue: dense store + bias
    const int b  = m_base >> 10;
    const int t0 = m_base & 1023;
#pragma unroll
    for (int ctl = 0; ctl < 4; ++ctl) {
        const int i  = (wave * 4 + ctl) * 16 + col;
        const int c  = i >> 7, df = i & 127;
        const int f  = chunk * CHUNK + df;
        if (f >= F_DIM) continue;
        const float bv = bias_g[c * F_DIM + f];
        float* orow = out + ((size_t)(b * 2 + c) * T_DIM + t0) * F_DIM + f;
#pragma unroll
        for (int mf = 0; mf < 2; ++mf)
#pragma unroll
            for (int reg = 0; reg < 4; ++reg) {
                const int r = mf * 16 + kg * 4 + reg;
                orow[(size_t)r * F_DIM] = acc[ctl][mf][reg] + bv;
            }
    }
}

extern "C" void kernel_launch(void* const* d_in, const int* in_sizes, int n_in,
                              void* d_out, int out_size, void* d_ws, size_t ws_size,
                              hipStream_t stream) {
    const float* x      = (const float*)d_in[0];
    const float* pre_w  = (const float*)d_in[1];
    const float* pre_b  = (const float*)d_in[2];
    const float* post_w = (const float*)d_in[3];
    const float* post_b = (const float*)d_in[4];
    const int*   idx    = (const int*)d_in[5];
    const float* melw   = (const float*)d_in[6];
    const float* mask   = (const float*)d_in[7];
    const float* ola    = (const float*)d_in[8];
    float* out = (float*)d_out;

    const int W   = in_sizes[5] / K_BANDS;   // <= 112
    const int din = 2 * W;

    // workspace layout
    const size_t mf_bytes   = (size_t)NCHUNK * K2 * OC * 4;          // 6,488,064
    const size_t bias_bytes = 8448;                                  // 2050*4 pad
    float*          Mf     = (float*)d_ws;
    float*          bias_g = (float*)((char*)d_ws + mf_bytes);
    unsigned short* preT   = (unsigned short*)((char*)d_ws + mf_bytes + bias_bytes);
    const size_t frag_bytes = (size_t)K_BANDS * NKTC * NMT * 64 * 8 * 2; // 3,670,016
    unsigned short* postP  = (unsigned short*)((char*)preT + frag_bytes);
    unsigned short* Mb     = (unsigned short*)((char*)postP + frag_bytes);

    hipMemsetAsync(d_ws, 0, mf_bytes + bias_bytes, stream);

    bs_pack_preT<<<dim3(K_BANDS, NKTC), 256, 0, stream>>>(pre_w, melw, mask,
                                                          preT, W, din);
    bs_pack_post<<<dim3(K_BANDS, NKTC), 256, 0, stream>>>(post_w, idx, melw,
                                                          mask, ola, postP,
                                                          W, din);
    bs_compose<0><<<K_BANDS / 2, 256, 0, stream>>>(preT, postP, pre_b, post_w,
                                                   post_b, idx, melw, mask, ola,
                                                   Mf, bias_g, W, din);
    bs_compose<1><<<K_BANDS / 2, 256, 0, stream>>>(preT, postP, pre_b, post_w,
                                                   post_b, idx, melw, mask, ola,
                                                   Mf, bias_g, W, din);
    bs_mk_bf16<<<dim3(NCHUNK, KT2), 256, 0, stream>>>(Mf, Mb);

    bs_banded<<<dim3(NCHUNK, (B_DIM * T_DIM) / M_TILE), 256, 0, stream>>>(
        x, Mb, bias_g, out);
}

// Round 8
// 107.145 us; speedup vs baseline: 1.9818x; 1.9818x over previous
//
#include <hip/hip_runtime.h>

// BandSplit R8: banded-matrix composition (R7) with compose parallelized:
// grid (64 bands x 14 mt), atomicAdd scatter into Mf/bias (no parity
// serialization), bias dot-product in its own kernel. Main = one dense
// banded GEMM (9 f-chunks x 128 t-tiles), plain coalesced stores.

#define K_BANDS 64
#define COUT_D  128
#define T_DIM   1024
#define B_DIM   4
#define F_DIM   1025
#define WPAD    112      // padded band width (W <= 112, verified R2-R7)
#define DINP    224      // 2*WPAD, channel-blocked j/i = c*112 + wi
#define NMT     14       // DINP/16 tiles
#define NKTC    4        // 128/32 compose-K tiles
#define CHUNK   128      // output f-bins per chunk
#define NCHUNK  9        // ceil(1025/128)
#define WIN     352      // 112 + 128 + 112 input window
#define K2      704      // 2*WIN
#define KT2     22       // K2/32
#define OC      256      // out cols per chunk (2ch x 128)
#define NCT     16       // OC/16
#define M_TILE  32       // rows per main block
#define SXLD    712      // s_x row stride (shorts): 356 dw %32=4 -> 2-way free

typedef __attribute__((ext_vector_type(8))) short bf16x8;
typedef __attribute__((ext_vector_type(4))) float f32x4;

__device__ __forceinline__ unsigned short f2bf(float f) {
    unsigned u = __builtin_bit_cast(unsigned, f);
    u += 0x7FFFu + ((u >> 16) & 1u);          // RNE
    return (unsigned short)(u >> 16);
}
__device__ __forceinline__ void st8(unsigned short* o, const unsigned short* v) {
    *(ushort4*)(o)     = make_ushort4(v[0], v[1], v[2], v[3]);
    *(ushort4*)(o + 4) = make_ushort4(v[4], v[5], v[6], v[7]);
}

struct alignas(4) f4u { float v[4]; };        // dword-aligned 16B load

// ---- pack pre'^T as MFMA A-frags: (k, kt over o, mt over j, lane, 8)
__global__ __launch_bounds__(256) void bs_pack_preT(
    const float* __restrict__ pre_w, const float* __restrict__ melw,
    const float* __restrict__ mask, unsigned short* __restrict__ dst,
    int W, int din)
{
    const int k = blockIdx.x, kt = blockIdx.y;
    for (int q = threadIdx.x; q < NMT * 64; q += 256) {
        const int mt = q >> 6, lane = q & 63;
        const int j  = mt * 16 + (lane & 15);
        const int kg = lane >> 4;
        const int cc = (j >= WPAD);
        const int wi = j - cc * WPAD;
        float wt = 0.f;
        if (wi < W) wt = melw[k * W + wi] * mask[k * W + wi];
        unsigned short v[8];
#pragma unroll
        for (int e = 0; e < 8; ++e) {
            const int o = kt * 32 + kg * 8 + e;
            const float f = (wt != 0.f)
                ? wt * pre_w[((size_t)k * din + (2 * wi + cc)) * COUT_D + o] : 0.f;
            v[e] = f2bf(f);
        }
        st8(dst + ((((size_t)k * NKTC + kt) * NMT + mt) * 64 + lane) * 8, v);
    }
}

// ---- pack post' as MFMA B-frags: (k, kt over o, ct over i, lane, 8), * sc(i)
__global__ __launch_bounds__(256) void bs_pack_post(
    const float* __restrict__ post_w, const int* __restrict__ idx,
    const float* __restrict__ melw, const float* __restrict__ mask,
    const float* __restrict__ ola, unsigned short* __restrict__ dst,
    int W, int din)
{
    const int k = blockIdx.x, kt = blockIdx.y;
    for (int q = threadIdx.x; q < NMT * 64; q += 256) {
        const int ct = q >> 6, lane = q & 63;
        const int col = lane & 15, kg = lane >> 4;
        const int i  = ct * 16 + col;
        const int cc = (i >= WPAD);
        const int wi = i - cc * WPAD;
        float sc = 0.f;
        if (wi < W) {
            const float mw = melw[k * W + wi] * mask[k * W + wi];
            if (mw != 0.f) sc = 1.0f / ola[idx[k * W + wi]];
        }
        unsigned short v[8];
#pragma unroll
        for (int e = 0; e < 8; ++e) {
            const int o = kt * 32 + kg * 8 + e;
            const float f = (sc != 0.f)
                ? sc * post_w[((size_t)k * COUT_D + o) * din + 2 * wi + cc] : 0.f;
            v[e] = f2bf(f);
        }
        st8(dst + ((((size_t)k * NKTC + kt) * NMT + ct) * 64 + lane) * 8, v);
    }
}

// ---- compose A_k = pre'^T x post' (224x224, K=128), atomicAdd into banded
// Mf32.  grid (K_BANDS, NMT): block owns one mt row; waves split nt.
__global__ __launch_bounds__(256) void bs_compose(
    const unsigned short* __restrict__ preT,
    const unsigned short* __restrict__ postP,
    const int* __restrict__ idx, const float* __restrict__ melw,
    const float* __restrict__ mask,
    float* __restrict__ Mf, int W)
{
    __shared__ unsigned char s_flag[DINP];
    const int k   = blockIdx.x;
    const int mt  = blockIdx.y;
    const int tid = threadIdx.x;
    const int f0  = idx[(size_t)k * W];

    if (tid < DINP) {
        const int cc = tid >= WPAD, wi = tid - cc * WPAD;
        s_flag[tid] = (wi < W) && (melw[k * W + wi] * mask[k * W + wi] != 0.f);
    }
    __syncthreads();

    const int lane = tid & 63, wave = tid >> 6;
    const int col  = lane & 15, kg  = lane >> 4;
    const bf16x8* ap = (const bf16x8*)(preT  + (size_t)k * NKTC * NMT * 512);
    const bf16x8* bp = (const bf16x8*)(postP + (size_t)k * NKTC * NMT * 512);

    bf16x8 a[NKTC];
#pragma unroll
    for (int kt = 0; kt < NKTC; ++kt) a[kt] = ap[(kt * NMT + mt) * 64 + lane];

    for (int nt = wave; nt < NMT; nt += 4) {
        f32x4 acc = (f32x4){0.f, 0.f, 0.f, 0.f};
#pragma unroll
        for (int kt = 0; kt < NKTC; ++kt)
            acc = __builtin_amdgcn_mfma_f32_16x16x32_bf16(
                a[kt], bp[(kt * NMT + nt) * 64 + lane], acc, 0, 0, 0);
        const int i_loc = nt * 16 + col;
        if (!s_flag[i_loc]) continue;
        const int c  = i_loc >= WPAD, wi = i_loc - c * WPAD;
        const int f  = f0 + wi;                // output bin
        const int ch = f >> 7, df = f & 127;
        const int lo = (ch << 7) - WPAD;
        const size_t colIdx = (size_t)(c * CHUNK + df);
#pragma unroll
        for (int reg = 0; reg < 4; ++reg) {
            const int j_loc = mt * 16 + kg * 4 + reg;
            if (!s_flag[j_loc]) continue;
            const int c2 = j_loc >= WPAD, wi2 = j_loc - c2 * WPAD;
            const int jj = f0 + wi2 - lo;      // in [1, 350]
            atomicAdd(Mf + ((size_t)ch * K2 + c2 * WIN + jj) * OC + colIdx,
                      acc[reg]);
        }
    }
}

// ---- bias[(c,f)] += sc * (pre_b . post_w[:, i] + post_b[i]) per band
__global__ __launch_bounds__(256) void bs_bias(
    const float* __restrict__ pre_b,  const float* __restrict__ post_w,
    const float* __restrict__ post_b, const int* __restrict__ idx,
    const float* __restrict__ melw,   const float* __restrict__ mask,
    const float* __restrict__ ola, float* __restrict__ bias_g,
    int W, int din)
{
    const int k   = blockIdx.x;
    const int tid = threadIdx.x;
    if (tid >= DINP) return;
    const int c = tid >= WPAD, wi = tid - c * WPAD;
    if (wi >= W) return;
    if (melw[k * W + wi] * mask[k * W + wi] == 0.f) return;
    const int f = idx[k * W + wi];
    float v = post_b[(size_t)k * din + 2 * wi + c];
    for (int o = 0; o < COUT_D; ++o)
        v += pre_b[k * COUT_D + o]
             * post_w[((size_t)k * COUT_D + o) * din + 2 * wi + c];
    atomicAdd(bias_g + c * F_DIM + f, v / ola[f]);
}

// ---- convert banded Mf32 -> bf16 B-frags: (chunk, kt, ct, lane, 8)
__global__ __launch_bounds__(256) void bs_mk_bf16(
    const float* __restrict__ Mf, unsigned short* __restrict__ Mb)
{
    const int chunk = blockIdx.x, kt = blockIdx.y;
    for (int q = threadIdx.x; q < NCT * 64; q += 256) {
        const int ct = q >> 6, lane = q & 63;
        const int col = lane & 15, kg = lane >> 4;
        unsigned short v[8];
#pragma unroll
        for (int e = 0; e < 8; ++e) {
            const int jp = kt * 32 + kg * 8 + e;
            v[e] = f2bf(Mf[((size_t)chunk * K2 + jp) * OC + ct * 16 + col]);
        }
        st8(Mb + ((((size_t)chunk * KT2 + kt) * NCT + ct) * 64 + lane) * 8, v);
    }
}

// ---- main: out_row = M . x_window + bias.  Plain dense stores, no memset.
__global__ __launch_bounds__(256) void bs_banded(
    const float* __restrict__ x, const unsigned short* __restrict__ Mb,
    const float* __restrict__ bias_g, float* __restrict__ out)
{
    __shared__ unsigned short s_x[M_TILE][SXLD];

    const int chunk  = blockIdx.x;
    const int m_base = blockIdx.y * M_TILE;
    const int tid    = threadIdx.x;
    const int lo     = chunk * CHUNK - WPAD;      // may be negative / past end

    // stage raw x window -> bf16 LDS (weights live in M; OOB -> clamped addr,
    // values killed by zero M rows)
    for (int p = tid; p < M_TILE * 2 * 88; p += 256) {
        const int seg = p / 88, q = p - seg * 88;
        const int row = seg >> 1, c = seg & 1;
        const int m = m_base + row, b = m >> 10, t = m & 1023;
        const float* xr = x + ((size_t)(b * 2 + c) * T_DIM + t) * F_DIM;
        const int fl = lo + 4 * q;
        float v0, v1, v2, v3;
        if (fl >= 0 && fl + 4 <= F_DIM) {
            const f4u vv = *reinterpret_cast<const f4u*>(xr + fl);
            v0 = vv.v[0]; v1 = vv.v[1]; v2 = vv.v[2]; v3 = vv.v[3];
        } else {
            const int e0 = min(max(fl, 0),     F_DIM - 1);
            const int e1 = min(max(fl + 1, 0), F_DIM - 1);
            const int e2 = min(max(fl + 2, 0), F_DIM - 1);
            const int e3 = min(max(fl + 3, 0), F_DIM - 1);
            v0 = xr[e0]; v1 = xr[e1]; v2 = xr[e2]; v3 = xr[e3];
        }
        const unsigned w0 = (unsigned)f2bf(v0) | ((unsigned)f2bf(v1) << 16);
        const unsigned w1 = (unsigned)f2bf(v2) | ((unsigned)f2bf(v3) << 16);
        unsigned* d = (unsigned*)&s_x[row][c * WIN + 4 * q];
        d[0] = w0; d[1] = w1;
    }
    __syncthreads();

    const int lane = tid & 63, wave = tid >> 6;
    const int col  = lane & 15, kg  = lane >> 4;

    f32x4 acc[4][2];
#pragma unroll
    for (int ctl = 0; ctl < 4; ++ctl)
#pragma unroll
        for (int mf = 0; mf < 2; ++mf) acc[ctl][mf] = (f32x4){0.f, 0.f, 0.f, 0.f};

    const bf16x8* bp = (const bf16x8*)(Mb + (size_t)chunk * KT2 * NCT * 512);
    bf16x8 bnx[4];
#pragma unroll
    for (int ctl = 0; ctl < 4; ++ctl)
        bnx[ctl] = bp[(size_t)(0 * NCT + wave * 4 + ctl) * 64 + lane];

    for (int kt = 0; kt < KT2; ++kt) {
        bf16x8 bc[4];
#pragma unroll
        for (int ctl = 0; ctl < 4; ++ctl) bc[ctl] = bnx[ctl];
        if (kt + 1 < KT2) {
#pragma unroll
            for (int ctl = 0; ctl < 4; ++ctl)
                bnx[ctl] = bp[(size_t)((kt + 1) * NCT + wave * 4 + ctl) * 64 + lane];
        }
        const bf16x8 a0 = *(const bf16x8*)&s_x[col][kt * 32 + kg * 8];
        const bf16x8 a1 = *(const bf16x8*)&s_x[16 + col][kt * 32 + kg * 8];
#pragma unroll
        for (int ctl = 0; ctl < 4; ++ctl) {
            acc[ctl][0] = __builtin_amdgcn_mfma_f32_16x16x32_bf16(
                a0, bc[ctl], acc[ctl][0], 0, 0, 0);
            acc[ctl][1] = __builtin_amdgcn_mfma_f32_16x16x32_bf16(
                a1, bc[ctl], acc[ctl][1], 0, 0, 0);
        }
    }

    // epilogue: dense store + bias
    const int b  = m_base >> 10;
    const int t0 = m_base & 1023;
#pragma unroll
    for (int ctl = 0; ctl < 4; ++ctl) {
        const int i  = (wave * 4 + ctl) * 16 + col;
        const int c  = i >> 7, df = i & 127;
        const int f  = chunk * CHUNK + df;
        if (f >= F_DIM) continue;
        const float bv = bias_g[c * F_DIM + f];
        float* orow = out + ((size_t)(b * 2 + c) * T_DIM + t0) * F_DIM + f;
#pragma unroll
        for (int mf = 0; mf < 2; ++mf)
#pragma unroll
            for (int reg = 0; reg < 4; ++reg) {
                const int r = mf * 16 + kg * 4 + reg;
                orow[(size_t)r * F_DIM] = acc[ctl][mf][reg] + bv;
            }
    }
}

extern "C" void kernel_launch(void* const* d_in, const int* in_sizes, int n_in,
                              void* d_out, int out_size, void* d_ws, size_t ws_size,
                              hipStream_t stream) {
    const float* x      = (const float*)d_in[0];
    const float* pre_w  = (const float*)d_in[1];
    const float* pre_b  = (const float*)d_in[2];
    const float* post_w = (const float*)d_in[3];
    const float* post_b = (const float*)d_in[4];
    const int*   idx    = (const int*)d_in[5];
    const float* melw   = (const float*)d_in[6];
    const float* mask   = (const float*)d_in[7];
    const float* ola    = (const float*)d_in[8];
    float* out = (float*)d_out;

    const int W   = in_sizes[5] / K_BANDS;   // <= 112
    const int din = 2 * W;

    // workspace layout
    const size_t mf_bytes   = (size_t)NCHUNK * K2 * OC * 4;          // 6,488,064
    const size_t bias_bytes = 8448;                                  // 2050*4 pad
    float*          Mf     = (float*)d_ws;
    float*          bias_g = (float*)((char*)d_ws + mf_bytes);
    unsigned short* preT   = (unsigned short*)((char*)d_ws + mf_bytes + bias_bytes);
    const size_t frag_bytes = (size_t)K_BANDS * NKTC * NMT * 64 * 8 * 2; // 3,670,016
    unsigned short* postP  = (unsigned short*)((char*)preT + frag_bytes);
    unsigned short* Mb     = (unsigned short*)((char*)postP + frag_bytes);

    hipMemsetAsync(d_ws, 0, mf_bytes + bias_bytes, stream);

    bs_pack_preT<<<dim3(K_BANDS, NKTC), 256, 0, stream>>>(pre_w, melw, mask,
                                                          preT, W, din);
    bs_pack_post<<<dim3(K_BANDS, NKTC), 256, 0, stream>>>(post_w, idx, melw,
                                                          mask, ola, postP,
                                                          W, din);
    bs_compose<<<dim3(K_BANDS, NMT), 256, 0, stream>>>(preT, postP, idx, melw,
                                                       mask, Mf, W);
    bs_bias<<<K_BANDS, 256, 0, stream>>>(pre_b, post_w, post_b, idx, melw,
                                         mask, ola, bias_g, W, din);
    bs_mk_bf16<<<dim3(NCHUNK, KT2), 256, 0, stream>>>(Mf, Mb);

    bs_banded<<<dim3(NCHUNK, (B_DIM * T_DIM) / M_TILE), 256, 0, stream>>>(
        x, Mb, bias_g, out);
}